// Round 6
// baseline (15.833 us; speedup 1.0000x reference)
//
#include <hip/hip_runtime.h>
#include <hip/hip_bf16.h>
#include <math.h>

// Shapes fixed by reference: B=2, L=385, C=128, N=384, 2C=256
// Verified identity (rounds 0-5 all passed):
//   out[b,1+i,c] = b[c] + sum_{kk=0}^{255} (coefA[b,kk]*F[b,i,kk&127] + coefB[b,kk]) * W[c,kk]
//     coefA[kk] = -s_kk (kk<128) | gamma[kk] (kk>=128)
//     coefB[kk] = fac_kk = s_kk*M_kk + beta[kk] (kk<128) | beta[kk] (kk>=128)
//     s_k = gamma[k]/sqrt(var_j F[:,k]+eps);  M_k = sum_j softmax_j(s_k F[j,k]) F[j,k]
// Two kernels: prep (6 blocks: per-batch stats once + W->bf16 once + cls copy)
// then main (24 blocks: As build + 1 barrier + MFMA with W fragments loaded
// straight from global as registers).

#define B_  2
#define L_  385
#define C_  128
#define N_  384
#define LC_ (L_ * C_)        // 49280
#define EPS_ 1e-5f
#define MROWS_ 32
#define RB_  (N_ / MROWS_)   // 12
#define LOG2E_ 1.44269504088896340736f

typedef short short8 __attribute__((ext_vector_type(8)));
typedef float f32x4 __attribute__((ext_vector_type(4)));

union V16 { ushort us[8]; uint4 v4; };
union U16 { uint4 v4; short8 s8; };

__device__ inline ushort f2bf(float f) {
  __hip_bfloat16 hb = __float2bfloat16(f);
  return __builtin_bit_cast(ushort, hb);
}

__device__ inline float fast_exp2(float xv) {
#if __has_builtin(__builtin_amdgcn_exp2f)
  return __builtin_amdgcn_exp2f(xv);
#else
  float r;
  asm("v_exp_f32 %0, %1" : "=v"(r) : "v"(xv));
  return r;
#endif
}

// ---------------------------------------------------------------------------
// Prep: blocks 0-1 = per-batch stats (once), blocks 2-5 = W->bf16 + cls copy.
// ---------------------------------------------------------------------------
__global__ __launch_bounds__(1024, 1) void lnp_prep(
    const float* __restrict__ x, const float* __restrict__ gamma,
    const float* __restrict__ beta, const float* __restrict__ W,
    float* __restrict__ wsNegS, float* __restrict__ wsFac,
    ushort* __restrict__ wsWbf, float* __restrict__ out) {
  const int blk = blockIdx.x;
  const int t   = threadIdx.x;

  if (blk >= 2) {
    // ---- W convert: 8192 elems per block, row-major bf16 [c][kk] ----
    const int base = (blk - 2) * 8192 + t * 8;
    const float4 wa  = *(const float4*)&W[base];
    const float4 wb2 = *(const float4*)&W[base + 4];
    V16 pk;
    pk.us[0] = f2bf(wa.x);  pk.us[1] = f2bf(wa.y);
    pk.us[2] = f2bf(wa.z);  pk.us[3] = f2bf(wa.w);
    pk.us[4] = f2bf(wb2.x); pk.us[5] = f2bf(wb2.y);
    pk.us[6] = f2bf(wb2.z); pk.us[7] = f2bf(wb2.w);
    *(uint4*)&wsWbf[base] = pk.v4;
    // cls-token passthrough
    if (blk == 2 && t < C_) out[t] = x[t];
    if (blk == 3 && t < C_) out[LC_ + t] = x[LC_ + t];
    return;
  }

  // ---- stats for batch b = blk ----
  __shared__ __align__(16) float p1[16][128], p2[16][128];
  __shared__ float sA[128], slA[128], shA[128];

  const int b  = blk;
  const float* Fb = x + (size_t)b * LC_ + C_;   // F[j][c] = Fb[j*128+c]
  const int tc = t & 31;
  const int c4 = tc * 4;
  const int h  = t >> 5;   // 0..31, rows h*12..h*12+11
  const int w  = t >> 6;   // wave 0..15
  const int l  = t & 63;

  float4 v[12];
  {
    const float* p = Fb + (size_t)(h * 12) * C_ + c4;
#pragma unroll
    for (int r = 0; r < 12; ++r)
      v[r] = *(const float4*)(p + (size_t)r * C_);

    float ax = 0.f, ay = 0.f, az = 0.f, aw = 0.f;
    float qx = 0.f, qy = 0.f, qz = 0.f, qw = 0.f;
#pragma unroll
    for (int r = 0; r < 12; ++r) {
      ax += v[r].x; qx = fmaf(v[r].x, v[r].x, qx);
      ay += v[r].y; qy = fmaf(v[r].y, v[r].y, qy);
      az += v[r].z; qz = fmaf(v[r].z, v[r].z, qz);
      aw += v[r].w; qw = fmaf(v[r].w, v[r].w, qw);
    }
    // in-wave pre-reduce: combine h pairs (lanes l and l^32 share channels)
    ax += __shfl_xor(ax, 32); ay += __shfl_xor(ay, 32);
    az += __shfl_xor(az, 32); aw += __shfl_xor(aw, 32);
    qx += __shfl_xor(qx, 32); qy += __shfl_xor(qy, 32);
    qz += __shfl_xor(qz, 32); qw += __shfl_xor(qw, 32);
    if (l < 32) {
      float4 s1 = {ax, ay, az, aw};
      float4 s2 = {qx, qy, qz, qw};
      *(float4*)&p1[w][c4] = s1;
      *(float4*)&p2[w][c4] = s2;
    }
  }
  __syncthreads();

  if (t < 128) {
    float s1 = 0.f, s2 = 0.f;
#pragma unroll
    for (int g = 0; g < 16; ++g) { s1 += p1[g][t]; s2 += p2[g][t]; }
    const float mean = s1 * (1.0f / N_);
    const float var  = fmaxf(s2 * (1.0f / N_) - mean * mean, 0.0f);
    const float s    = gamma[t] * rsqrtf(var + EPS_);
    const float sl   = s * LOG2E_;
    sA[t] = s; slA[t] = sl; shA[t] = sl * mean;
    wsNegS[b * 128 + t] = -s;
  }
  __syncthreads();

  {
    const float4 sl4 = *(const float4*)&slA[c4];
    const float4 sh4 = *(const float4*)&shA[c4];
    float ex = 0.f, ey = 0.f, ez = 0.f, ew = 0.f;
    float fx = 0.f, fy = 0.f, fz = 0.f, fw = 0.f;
#pragma unroll
    for (int r = 0; r < 12; ++r) {
      const float e0 = fast_exp2(fmaf(sl4.x, v[r].x, -sh4.x));
      const float e1 = fast_exp2(fmaf(sl4.y, v[r].y, -sh4.y));
      const float e2 = fast_exp2(fmaf(sl4.z, v[r].z, -sh4.z));
      const float e3 = fast_exp2(fmaf(sl4.w, v[r].w, -sh4.w));
      ex += e0; fx = fmaf(e0, v[r].x, fx);
      ey += e1; fy = fmaf(e1, v[r].y, fy);
      ez += e2; fz = fmaf(e2, v[r].z, fz);
      ew += e3; fw = fmaf(e3, v[r].w, fw);
    }
    ex += __shfl_xor(ex, 32); ey += __shfl_xor(ey, 32);
    ez += __shfl_xor(ez, 32); ew += __shfl_xor(ew, 32);
    fx += __shfl_xor(fx, 32); fy += __shfl_xor(fy, 32);
    fz += __shfl_xor(fz, 32); fw += __shfl_xor(fw, 32);
    if (l < 32) {
      float4 se = {ex, ey, ez, ew};
      float4 sf = {fx, fy, fz, fw};
      *(float4*)&p1[w][c4] = se;
      *(float4*)&p2[w][c4] = sf;
    }
  }
  __syncthreads();

  if (t < 128) {
    float se = 0.f, sf = 0.f;
#pragma unroll
    for (int g = 0; g < 16; ++g) { se += p1[g][t]; sf += p2[g][t]; }
    wsFac[b * 128 + t] = fmaf(sA[t], sf / se, beta[t]);
  }
}

// ---------------------------------------------------------------------------
// Main: 24 blocks x 1024 thr. As build (1 LDS tile) + 1 barrier + MFMA with
// B fragments loaded from global wsWbf into registers.
// ---------------------------------------------------------------------------
__global__ __launch_bounds__(1024, 1) void lnp_main(
    const float* __restrict__ x, const float* __restrict__ gamma,
    const float* __restrict__ beta, const float* __restrict__ bvec,
    const float* __restrict__ wsNegS, const float* __restrict__ wsFac,
    const ushort* __restrict__ wsWbf, float* __restrict__ out) {
  __shared__ __align__(16) ushort As[MROWS_ * 256];  // [i][kk^((i&7)<<3)] bf16

  const int blk = blockIdx.x;
  const int b   = blk / RB_;
  const int rt  = blk % RB_;
  const int r0  = rt * MROWS_;
  const int t   = threadIdx.x;
  const int wv  = t >> 6;
  const int l   = t & 63;
  const int l16 = l & 15;
  const int lg  = l >> 4;
  const int tn  = wv & 7;
  const int tm  = wv >> 3;
  const int bc  = tn * 16 + l16;   // output col
  const int ar  = tm * 16 + l16;   // A row (local)

  // ---- As-build loads (needed first; issue before the W fragments) ----
  const int ai  = t >> 5;          // local row 0..31
  const int kk0 = (t & 31) * 8;
  const int ks  = kk0 & 127;
  const float* fp = x + (size_t)b * LC_ + C_ + (size_t)(r0 + ai) * C_ + ks;
  const float4 af0 = *(const float4*)fp;
  const float4 af1 = *(const float4*)(fp + 4);
  const float* pA = (kk0 < 128) ? (wsNegS + b * 128 + kk0) : (gamma + kk0);
  const float* pB = (kk0 < 128) ? (wsFac + b * 128 + kk0) : (beta + kk0);
  const float4 cA0 = *(const float4*)pA;
  const float4 cA1 = *(const float4*)(pA + 4);
  const float4 cB0 = *(const float4*)pB;
  const float4 cB1 = *(const float4*)(pB + 4);

  // ---- W fragment + bias loads (used after the barrier; stay in flight) ----
  U16 wb[8];
  const ushort* wrow = wsWbf + bc * 256 + lg * 8;
#pragma unroll
  for (int kt = 0; kt < 8; ++kt)
    wb[kt].v4 = *(const uint4*)(wrow + kt * 32);
  const float bb = bvec[bc];

  // ---- build As row chunk ----
  {
    V16 pk;
    pk.us[0] = f2bf(fmaf(cA0.x, af0.x, cB0.x));
    pk.us[1] = f2bf(fmaf(cA0.y, af0.y, cB0.y));
    pk.us[2] = f2bf(fmaf(cA0.z, af0.z, cB0.z));
    pk.us[3] = f2bf(fmaf(cA0.w, af0.w, cB0.w));
    pk.us[4] = f2bf(fmaf(cA1.x, af1.x, cB1.x));
    pk.us[5] = f2bf(fmaf(cA1.y, af1.y, cB1.y));
    pk.us[6] = f2bf(fmaf(cA1.z, af1.z, cB1.z));
    pk.us[7] = f2bf(fmaf(cA1.w, af1.w, cB1.w));
    *(uint4*)&As[ai * 256 + (kk0 ^ ((ai & 7) << 3))] = pk.v4;
  }
  __syncthreads();

  // ---- MFMA: 16 waves x one 16x16 tile, K=256 (verified layout) ----
  {
    const int abase = ar * 256;
    const int aswz  = (ar & 7) << 3;
    f32x4 acc = {0.f, 0.f, 0.f, 0.f};
#pragma unroll
    for (int kt = 0; kt < 8; ++kt) {
      const int kk = kt * 32 + lg * 8;
      const short8 av = *(const short8*)&As[abase + (kk ^ aswz)];
      acc = __builtin_amdgcn_mfma_f32_16x16x32_bf16(av, wb[kt].s8, acc, 0, 0, 0);
    }
    float* ob = out + (size_t)b * LC_;
#pragma unroll
    for (int r = 0; r < 4; ++r) {
      const int m = tm * 16 + lg * 4 + r;
      ob[(size_t)(1 + r0 + m) * C_ + bc] = acc[r] + bb;
    }
  }
}

extern "C" void kernel_launch(void* const* d_in, const int* in_sizes, int n_in,
                              void* d_out, int out_size, void* d_ws, size_t ws_size,
                              hipStream_t stream) {
  const float* x     = (const float*)d_in[0];
  const float* gamma = (const float*)d_in[1];
  const float* beta  = (const float*)d_in[2];
  const float* W     = (const float*)d_in[3];
  const float* bvec  = (const float*)d_in[4];
  float* out = (float*)d_out;

  float*  wsNegS = (float*)d_ws;               // 256 floats
  float*  wsFac  = wsNegS + 256;               // 256 floats
  ushort* wsWbf  = (ushort*)(wsNegS + 512);    // 32768 bf16 (64 KB), 16B-aligned

  lnp_prep<<<6, 1024, 0, stream>>>(x, gamma, beta, W, wsNegS, wsFac, wsWbf, out);
  lnp_main<<<B_ * RB_, 1024, 0, stream>>>(x, gamma, beta, bvec,
                                          wsNegS, wsFac, wsWbf, out);
}

// Round 7
// 15.099 us; speedup vs baseline: 1.0486x; 1.0486x over previous
//
#include <hip/hip_runtime.h>
#include <hip/hip_bf16.h>
#include <math.h>

// Shapes fixed by reference: B=2, L=385, C=128, N=384, 2C=256
// Verified identity (rounds 0-6 all passed):
//   out[b,1+i,c] = b[c] + sum_{kk=0}^{255} (coefA[b,kk]*F[b,i,kk&127] + coefB[b,kk]) * W[c,kk]
//     coefA[kk] = -s_kk (kk<128) | gamma[kk] (kk>=128)
//     coefB[kk] = s_kk*M_kk + beta[kk] (kk<128) | beta[kk] (kk>=128)
//     s_k = gamma[k]/sqrt(var_j F[:,k]+eps);  M_k = sum_j softmax_j(s_k F[j,k]) F[j,k]
// Single fused kernel (R6's two-launch split regressed; dependent launches
// serialize). All global loads issued in phase 0 so their latency hides under
// the stats VALU work. shfl_xor(32) pre-reduction halves the t<128 finalize
// serial reads. Branch-free coef arrays make the As build single-shot.

#define B_  2
#define L_  385
#define C_  128
#define N_  384
#define LC_ (L_ * C_)
#define EPS_ 1e-5f
#define MROWS_ 32
#define RB_  (N_ / MROWS_)   // 12
#define NTHR_ 1024
#define LOG2E_ 1.44269504088896340736f

typedef short short8 __attribute__((ext_vector_type(8)));
typedef float f32x4 __attribute__((ext_vector_type(4)));

union V16 { ushort us[8]; uint4 v4; };

__device__ inline ushort f2bf(float f) {
  __hip_bfloat16 hb = __float2bfloat16(f);   // hw RNE
  return __builtin_bit_cast(ushort, hb);
}

__device__ inline float fast_exp2(float xv) {
#if __has_builtin(__builtin_amdgcn_exp2f)
  return __builtin_amdgcn_exp2f(xv);
#else
  float r;
  asm("v_exp_f32 %0, %1" : "=v"(r) : "v"(xv));
  return r;
#endif
}

__global__ __launch_bounds__(NTHR_, 1) void lnp_kernel(
    const float* __restrict__ x, const float* __restrict__ gamma,
    const float* __restrict__ beta, const float* __restrict__ W,
    const float* __restrict__ bvec, float* __restrict__ out) {
  __shared__ __align__(16) float p1[16][128], p2[16][128];
  __shared__ __align__(16) float slA[128], shA[128];
  __shared__ __align__(16) float coefA[256], coefB[256];
  __shared__ __align__(16) ushort Wb[128 * 256];    // [c][kk^((c&7)<<3)] bf16
  __shared__ __align__(16) ushort As[MROWS_ * 256]; // [i][kk^((i&7)<<3)] bf16

  const int blk = blockIdx.x;
  const int b   = blk / RB_;
  const int rt  = blk % RB_;
  const int r0  = rt * MROWS_;
  const int t   = threadIdx.x;
  const int l   = t & 63;
  const int w   = t >> 6;

  const float* Fb = x + (size_t)b * LC_ + C_;   // F[j][c] = Fb[j*128+c]

  // MFMA tile indices (needed early for bias prefetch)
  const int l16 = l & 15;
  const int lg  = l >> 4;
  const int tn  = w & 7;
  const int tm  = w >> 3;
  const int bc  = tn * 16 + l16;   // output col
  const int ar  = tm * 16 + l16;   // A row (local)

  // ================= phase 0: issue ALL global loads =================
  // stats F loads: thread owns channels c4..c4+3, rows h*12..h*12+11
  const int c4 = (t & 31) * 4;
  const int h  = t >> 5;
  float4 v[12];
  {
    const float* p = Fb + (size_t)(h * 12) * C_ + c4;
#pragma unroll
    for (int r = 0; r < 12; ++r)
      v[r] = *(const float4*)(p + (size_t)r * C_);
  }
  // As row loads: thread owns local row ai, kk chunk kk0..kk0+7
  const int ai  = t >> 5;
  const int kk0 = (t & 31) * 8;
  const int ks  = kk0 & 127;
  float4 af0, af1;
  {
    const float* fp = Fb + (size_t)(r0 + ai) * C_ + ks;
    af0 = *(const float4*)fp;
    af1 = *(const float4*)(fp + 4);
  }
  // W tile loads: thread owns row cW, 32-kk segment kb
  const int cW  = t >> 3;
  const int kb  = (t & 7) * 32;
  const int swzW = (cW & 7) << 3;
  float4 wv[8];
  {
    const float* wp = &W[cW * 256 + kb];
#pragma unroll
    for (int q = 0; q < 8; ++q) wv[q] = *(const float4*)(wp + q * 4);
  }
  const float bb = bvec[bc];

  // cls-token passthrough
  if (rt == 0 && t < C_)
    out[(size_t)b * LC_ + t] = x[(size_t)b * LC_ + t];

  // ================= Wb build (frees wv early) =================
#pragma unroll
  for (int q = 0; q < 4; ++q) {
    V16 pk;
    pk.us[0] = f2bf(wv[2 * q].x);     pk.us[1] = f2bf(wv[2 * q].y);
    pk.us[2] = f2bf(wv[2 * q].z);     pk.us[3] = f2bf(wv[2 * q].w);
    pk.us[4] = f2bf(wv[2 * q + 1].x); pk.us[5] = f2bf(wv[2 * q + 1].y);
    pk.us[6] = f2bf(wv[2 * q + 1].z); pk.us[7] = f2bf(wv[2 * q + 1].w);
    *(uint4*)&Wb[cW * 256 + ((kb + q * 8) ^ swzW)] = pk.v4;
  }

  // ================= stats pass 1: sum / sumsq =================
  {
    float ax = 0.f, ay = 0.f, az = 0.f, aw = 0.f;
    float qx = 0.f, qy = 0.f, qz = 0.f, qw = 0.f;
#pragma unroll
    for (int r = 0; r < 12; ++r) {
      ax += v[r].x; qx = fmaf(v[r].x, v[r].x, qx);
      ay += v[r].y; qy = fmaf(v[r].y, v[r].y, qy);
      az += v[r].z; qz = fmaf(v[r].z, v[r].z, qz);
      aw += v[r].w; qw = fmaf(v[r].w, v[r].w, qw);
    }
    // lanes l and l^32 own the same channels -> halve partial count in-wave
    ax += __shfl_xor(ax, 32); ay += __shfl_xor(ay, 32);
    az += __shfl_xor(az, 32); aw += __shfl_xor(aw, 32);
    qx += __shfl_xor(qx, 32); qy += __shfl_xor(qy, 32);
    qz += __shfl_xor(qz, 32); qw += __shfl_xor(qw, 32);
    if (l < 32) {
      float4 s1 = {ax, ay, az, aw};
      float4 s2 = {qx, qy, qz, qw};
      *(float4*)&p1[w][c4] = s1;
      *(float4*)&p2[w][c4] = s2;
    }
  }
  __syncthreads();  // B1 (also covers Wb writes)

  if (t < 128) {
    float s1 = 0.f, s2 = 0.f;
#pragma unroll
    for (int g = 0; g < 16; ++g) { s1 += p1[g][t]; s2 += p2[g][t]; }
    const float mean = s1 * (1.0f / N_);
    const float var  = fmaxf(s2 * (1.0f / N_) - mean * mean, 0.0f);
    const float s    = gamma[t] * rsqrtf(var + EPS_);
    const float sl   = s * LOG2E_;
    slA[t] = sl; shA[t] = sl * mean;
    coefA[t]       = -s;
    coefA[128 + t] = gamma[128 + t];
    coefB[128 + t] = beta[128 + t];
  }
  __syncthreads();  // B2

  // ================= stats pass 2: softmax moments (regs only) =================
  {
    const float4 sl4 = *(const float4*)&slA[c4];
    const float4 sh4 = *(const float4*)&shA[c4];
    float ex = 0.f, ey = 0.f, ez = 0.f, ew = 0.f;
    float fx = 0.f, fy = 0.f, fz = 0.f, fw = 0.f;
#pragma unroll
    for (int r = 0; r < 12; ++r) {
      const float e0 = fast_exp2(fmaf(sl4.x, v[r].x, -sh4.x));
      const float e1 = fast_exp2(fmaf(sl4.y, v[r].y, -sh4.y));
      const float e2 = fast_exp2(fmaf(sl4.z, v[r].z, -sh4.z));
      const float e3 = fast_exp2(fmaf(sl4.w, v[r].w, -sh4.w));
      ex += e0; fx = fmaf(e0, v[r].x, fx);
      ey += e1; fy = fmaf(e1, v[r].y, fy);
      ez += e2; fz = fmaf(e2, v[r].z, fz);
      ew += e3; fw = fmaf(e3, v[r].w, fw);
    }
    ex += __shfl_xor(ex, 32); ey += __shfl_xor(ey, 32);
    ez += __shfl_xor(ez, 32); ew += __shfl_xor(ew, 32);
    fx += __shfl_xor(fx, 32); fy += __shfl_xor(fy, 32);
    fz += __shfl_xor(fz, 32); fw += __shfl_xor(fw, 32);
    if (l < 32) {
      float4 se = {ex, ey, ez, ew};
      float4 sf = {fx, fy, fz, fw};
      *(float4*)&p1[w][c4] = se;
      *(float4*)&p2[w][c4] = sf;
    }
  }
  __syncthreads();  // B3

  if (t < 128) {
    float se = 0.f, sf = 0.f;
#pragma unroll
    for (int g = 0; g < 16; ++g) { se += p1[g][t]; sf += p2[g][t]; }
    coefB[t] = fmaf(-coefA[t], sf / se, beta[t]);
  }
  __syncthreads();  // B4

  // ================= As build: single-shot, branch-free =================
  {
    const float4 cA0 = *(const float4*)&coefA[kk0];
    const float4 cA1 = *(const float4*)&coefA[kk0 + 4];
    const float4 cB0 = *(const float4*)&coefB[kk0];
    const float4 cB1 = *(const float4*)&coefB[kk0 + 4];
    V16 pk;
    pk.us[0] = f2bf(fmaf(cA0.x, af0.x, cB0.x));
    pk.us[1] = f2bf(fmaf(cA0.y, af0.y, cB0.y));
    pk.us[2] = f2bf(fmaf(cA0.z, af0.z, cB0.z));
    pk.us[3] = f2bf(fmaf(cA0.w, af0.w, cB0.w));
    pk.us[4] = f2bf(fmaf(cA1.x, af1.x, cB1.x));
    pk.us[5] = f2bf(fmaf(cA1.y, af1.y, cB1.y));
    pk.us[6] = f2bf(fmaf(cA1.z, af1.z, cB1.z));
    pk.us[7] = f2bf(fmaf(cA1.w, af1.w, cB1.w));
    *(uint4*)&As[ai * 256 + (kk0 ^ ((ai & 7) << 3))] = pk.v4;
  }
  __syncthreads();  // B5

  // ================= MFMA: 16 waves x one 16x16 tile, K=256 =================
  {
    const int abase = ar * 256;
    const int aswz  = (ar & 7) << 3;
    const int bbase = bc * 256;
    const int bswz  = (bc & 7) << 3;
    f32x4 acc = {0.f, 0.f, 0.f, 0.f};
#pragma unroll
    for (int kt = 0; kt < 8; ++kt) {
      const int kk = kt * 32 + lg * 8;
      const short8 av = *(const short8*)&As[abase + (kk ^ aswz)];
      const short8 bv = *(const short8*)&Wb[bbase + (kk ^ bswz)];
      acc = __builtin_amdgcn_mfma_f32_16x16x32_bf16(av, bv, acc, 0, 0, 0);
    }
    float* ob = out + (size_t)b * LC_;
#pragma unroll
    for (int r = 0; r < 4; ++r) {
      const int m = tm * 16 + lg * 4 + r;
      ob[(size_t)(1 + r0 + m) * C_ + bc] = acc[r] + bb;
    }
  }
}

extern "C" void kernel_launch(void* const* d_in, const int* in_sizes, int n_in,
                              void* d_out, int out_size, void* d_ws, size_t ws_size,
                              hipStream_t stream) {
  const float* x     = (const float*)d_in[0];
  const float* gamma = (const float*)d_in[1];
  const float* beta  = (const float*)d_in[2];
  const float* W     = (const float*)d_in[3];
  const float* bvec  = (const float*)d_in[4];
  float* out = (float*)d_out;

  lnp_kernel<<<B_ * RB_, NTHR_, 0, stream>>>(x, gamma, beta, W, bvec, out);
}